// Round 1
// baseline (1611.794 us; speedup 1.0000x reference)
//
#include <hip/hip_runtime.h>
#include <math.h>

#define HDIM 256
#define NMOL 4096
#define NPROT 4096
#define NEDGE 65536
#define NG 32

// ---------------------------------------------------------------------------
// node embedding: out[i,c] = sum_k x[i,k]*w[k,c] + b[c]
// one block per node, 256 threads = 256 channels
__global__ __launch_bounds__(256) void k_node_embed(
    const float* __restrict__ x, const float* __restrict__ w,
    const float* __restrict__ b, float* __restrict__ out, int K) {
  const int i = blockIdx.x;
  const int c = threadIdx.x;
  float acc = b[c];
  for (int k = 0; k < K; ++k) acc += x[i * K + k] * w[k * HDIM + c];
  out[(size_t)i * HDIM + c] = acc;
}

// ---------------------------------------------------------------------------
// GINE aggregation with fused edge embedding:
// agg[dst,c] += relu(x[src,c] + ea[e,0]*we[0,c] + ea[e,1]*we[1,c] + be[c])
// one block per edge, 256 threads = channels
__global__ __launch_bounds__(256) void k_gine_agg(
    const float* __restrict__ x, const float* __restrict__ ea,
    const int* __restrict__ ei, const float* __restrict__ we,
    const float* __restrict__ be, float* __restrict__ agg, int E) {
  const int e = blockIdx.x;
  const int c = threadIdx.x;
  const int src = ei[e];
  const int dst = ei[E + e];
  const float a0 = ea[2 * e], a1 = ea[2 * e + 1];
  float m = x[(size_t)src * HDIM + c] + a0 * we[c] + a1 * we[HDIM + c] + be[c];
  if (m > 0.f) atomicAdd(&agg[(size_t)dst * HDIM + c], m);
}

// ---------------------------------------------------------------------------
// fp32 GEMM: C = act((A1 [+ A2]) @ W + bias), A [M,Kd] row-major, W [Kd,N].
// BM=BN=64, BK=16, 256 threads, 4x4 microtile.
template <bool RELU, bool HASA2>
__global__ __launch_bounds__(256) void k_gemm(
    const float* __restrict__ A1, const float* __restrict__ A2,
    const float* __restrict__ W, const float* __restrict__ bias,
    float* __restrict__ C, int M, int N, int Kd) {
  __shared__ float As[16][68];  // [k][m], pad 68 -> 2-way store conflicts max
  __shared__ float Ws[16][64];  // [k][n]
  const int t = threadIdx.x;
  const int bm = blockIdx.x * 64, bn = blockIdx.y * 64;
  const int tx = t & 15, ty = t >> 4;
  const int lr = t >> 2, lk = (t & 3) * 4;   // A-load: row, k-offset
  const int wk = t >> 4, wc = (t & 15) * 4;  // W-load: k, col-offset
  float acc[4][4] = {};
  for (int k0 = 0; k0 < Kd; k0 += 16) {
    float4 av = *(const float4*)&A1[(size_t)(bm + lr) * Kd + k0 + lk];
    if (HASA2) {
      float4 a2 = *(const float4*)&A2[(size_t)(bm + lr) * Kd + k0 + lk];
      av.x += a2.x; av.y += a2.y; av.z += a2.z; av.w += a2.w;
    }
    float4 wv = *(const float4*)&W[(size_t)(k0 + wk) * N + bn + wc];
    __syncthreads();  // protect previous iteration's LDS reads
    As[lk + 0][lr] = av.x; As[lk + 1][lr] = av.y;
    As[lk + 2][lr] = av.z; As[lk + 3][lr] = av.w;
    *(float4*)&Ws[wk][wc] = wv;
    __syncthreads();
#pragma unroll
    for (int k = 0; k < 16; ++k) {
      float4 a4 = *(const float4*)&As[k][ty * 4];
      float4 b4 = *(const float4*)&Ws[k][tx * 4];
      float aa[4] = {a4.x, a4.y, a4.z, a4.w};
      float bb[4] = {b4.x, b4.y, b4.z, b4.w};
#pragma unroll
      for (int i = 0; i < 4; ++i)
#pragma unroll
        for (int j = 0; j < 4; ++j) acc[i][j] += aa[i] * bb[j];
    }
  }
  float b0 = bias[bn + tx * 4 + 0], b1 = bias[bn + tx * 4 + 1];
  float b2 = bias[bn + tx * 4 + 2], b3 = bias[bn + tx * 4 + 3];
#pragma unroll
  for (int i = 0; i < 4; ++i) {
    float4 cv;
    cv.x = acc[i][0] + b0; cv.y = acc[i][1] + b1;
    cv.z = acc[i][2] + b2; cv.w = acc[i][3] + b3;
    if (RELU) {
      cv.x = fmaxf(cv.x, 0.f); cv.y = fmaxf(cv.y, 0.f);
      cv.z = fmaxf(cv.z, 0.f); cv.w = fmaxf(cv.w, 0.f);
    }
    *(float4*)&C[(size_t)(bm + ty * 4 + i) * N + bn + tx * 4] = cv;
  }
}

// ---------------------------------------------------------------------------
// fp32 flash attention, one block per (64-row q-tile, head).
// hd = 64, scale = 1/8. Out = Hin + softmax(Q K^T / 8) V   (residual fused)
// Softmax stats in registers (16-lane shfl reductions); P stays in registers,
// broadcast into PV via __shfl. LDS = Qs+Ks+Vs = 51.2 KB.
__global__ __launch_bounds__(256) void k_attn(
    const float* __restrict__ Q, const float* __restrict__ Kmat,
    const float* __restrict__ V, const float* __restrict__ Hin,
    float* __restrict__ Out, int nq, int nk) {
  __shared__ float Qs[64][68];  // [d][r], pre-scaled by 1/8
  __shared__ float Ks[64][68];  // [d][c]
  __shared__ float Vs[64][64];  // [c][d]
  const int t = threadIdx.x;
  const int h = blockIdx.y;
  const int q0 = blockIdx.x * 64;
  const int tx = t & 15, ty = t >> 4;

#pragma unroll
  for (int rep = 0; rep < 4; ++rep) {
    int idx = t + rep * 256;
    int r = idx >> 4;
    int d4 = (idx & 15) * 4;
    float4 qv = *(const float4*)&Q[(size_t)(q0 + r) * HDIM + h * 64 + d4];
    Qs[d4 + 0][r] = qv.x * 0.125f;
    Qs[d4 + 1][r] = qv.y * 0.125f;
    Qs[d4 + 2][r] = qv.z * 0.125f;
    Qs[d4 + 3][r] = qv.w * 0.125f;
  }

  float o[4][4] = {};
  float mrun[4] = {-1e30f, -1e30f, -1e30f, -1e30f};
  float lrun[4] = {};
  const int lanebase = (ty & 3) * 16;

  for (int k0 = 0; k0 < nk; k0 += 64) {
    __syncthreads();  // protect previous tile's Vs/Ks reads (and Qs stores, 1st iter)
#pragma unroll
    for (int rep = 0; rep < 4; ++rep) {
      int idx = t + rep * 256;
      int ck = idx >> 4;
      int d4 = (idx & 15) * 4;
      float4 kv = *(const float4*)&Kmat[(size_t)(k0 + ck) * HDIM + h * 64 + d4];
      Ks[d4 + 0][ck] = kv.x; Ks[d4 + 1][ck] = kv.y;
      Ks[d4 + 2][ck] = kv.z; Ks[d4 + 3][ck] = kv.w;
      *(float4*)&Vs[ck][d4] = *(const float4*)&V[(size_t)(k0 + ck) * HDIM + h * 64 + d4];
    }
    __syncthreads();

    // S = Qs^T Ks  (4x4 per thread)
    float s[4][4] = {};
#pragma unroll 8
    for (int d = 0; d < 64; ++d) {
      float4 a4 = *(const float4*)&Qs[d][ty * 4];
      float4 b4 = *(const float4*)&Ks[d][tx * 4];
      float aa[4] = {a4.x, a4.y, a4.z, a4.w};
      float bb[4] = {b4.x, b4.y, b4.z, b4.w};
#pragma unroll
      for (int i = 0; i < 4; ++i)
#pragma unroll
        for (int j = 0; j < 4; ++j) s[i][j] += aa[i] * bb[j];
    }

    // online softmax: row stats via 16-lane shfl reductions
    float p[4][4];
#pragma unroll
    for (int i = 0; i < 4; ++i) {
      float mt = fmaxf(fmaxf(s[i][0], s[i][1]), fmaxf(s[i][2], s[i][3]));
      mt = fmaxf(mt, __shfl_xor(mt, 1, 64));
      mt = fmaxf(mt, __shfl_xor(mt, 2, 64));
      mt = fmaxf(mt, __shfl_xor(mt, 4, 64));
      mt = fmaxf(mt, __shfl_xor(mt, 8, 64));
      float mn = fmaxf(mrun[i], mt);
      float alpha = __expf(mrun[i] - mn);
      mrun[i] = mn;
      float rs = 0.f;
#pragma unroll
      for (int j = 0; j < 4; ++j) {
        p[i][j] = __expf(s[i][j] - mn);
        rs += p[i][j];
      }
      rs += __shfl_xor(rs, 1, 64);
      rs += __shfl_xor(rs, 2, 64);
      rs += __shfl_xor(rs, 4, 64);
      rs += __shfl_xor(rs, 8, 64);
      lrun[i] = lrun[i] * alpha + rs;
#pragma unroll
      for (int j = 0; j < 4; ++j) o[i][j] *= alpha;
    }

    // O += P @ V : broadcast P chunks across the 16-lane row group via shfl
#pragma unroll 4
    for (int c4 = 0; c4 < 16; ++c4) {
#pragma unroll
      for (int cj = 0; cj < 4; ++cj) {
        float pb[4];
#pragma unroll
        for (int i = 0; i < 4; ++i) pb[i] = __shfl(p[i][cj], lanebase + c4, 64);
        float4 v4 = *(const float4*)&Vs[c4 * 4 + cj][tx * 4];
        float vv[4] = {v4.x, v4.y, v4.z, v4.w};
#pragma unroll
        for (int i = 0; i < 4; ++i)
#pragma unroll
          for (int j = 0; j < 4; ++j) o[i][j] += pb[i] * vv[j];
      }
    }
  }

#pragma unroll
  for (int i = 0; i < 4; ++i) {
    float inv = 1.0f / lrun[i];
    size_t row = (size_t)(q0 + ty * 4 + i);
    float4 hv = *(const float4*)&Hin[row * HDIM + h * 64 + tx * 4];
    float4 ov;
    ov.x = hv.x + o[i][0] * inv;
    ov.y = hv.y + o[i][1] * inv;
    ov.z = hv.z + o[i][2] * inv;
    ov.w = hv.w + o[i][3] * inv;
    *(float4*)&Out[row * HDIM + h * 64 + tx * 4] = ov;
  }
}

// ---------------------------------------------------------------------------
// segment sum into z[g*512 + c] (z pre-offset by +256 for prot), count per graph
__global__ __launch_bounds__(256) void k_segsum(
    const float* __restrict__ Hc, const int* __restrict__ batch,
    float* __restrict__ z, float* __restrict__ cnt) {
  const int i = blockIdx.x;
  const int c = threadIdx.x;
  const int g = batch[i];
  atomicAdd(&z[(size_t)g * 512 + c], Hc[(size_t)i * HDIM + c]);
  if (c == 0) atomicAdd(&cnt[g], 1.0f);
}

__global__ __launch_bounds__(256) void k_segdiv(float* __restrict__ z,
                                                const float* __restrict__ cnt) {
  const int idx = blockIdx.x * 256 + threadIdx.x;  // 32*512
  const int g = idx >> 9, c = idx & 511;
  const float cc = cnt[(c < 256) ? g : (32 + g)];
  z[idx] /= fmaxf(cc, 1.0f);
}

__global__ __launch_bounds__(256) void k_fc1(
    const float* __restrict__ z, const float* __restrict__ w,
    const float* __restrict__ b, float* __restrict__ out) {
  const int idx = blockIdx.x * 256 + threadIdx.x;  // 32*256
  const int r = idx >> 8, c = idx & 255;
  float acc = b[c];
  for (int k = 0; k < 512; ++k) acc += z[r * 512 + k] * w[k * HDIM + c];
  out[idx] = fmaxf(acc, 0.f);
}

__global__ __launch_bounds__(64) void k_fc2(
    const float* __restrict__ xin, const float* __restrict__ w,
    const float* __restrict__ b, float* __restrict__ out) {
  const int r = threadIdx.x;
  if (r < NG) {
    float acc = b[0];
    for (int k = 0; k < HDIM; ++k) acc += xin[r * HDIM + k] * w[k];
    out[r] = 1.0f / (1.0f + __expf(-acc));
  }
}

// ---------------------------------------------------------------------------
extern "C" void kernel_launch(void* const* d_in, const int* in_sizes, int n_in,
                              void* d_out, int out_size, void* d_ws, size_t ws_size,
                              hipStream_t stream) {
  const float* x_mol   = (const float*)d_in[0];
  const float* x_prot  = (const float*)d_in[1];
  const float* ea_mol  = (const float*)d_in[2];
  const float* ea_prot = (const float*)d_in[3];
  const int*   ei_mol  = (const int*)d_in[4];
  const int*   ei_prot = (const int*)d_in[5];
  const int*   b_mol   = (const int*)d_in[6];
  const int*   b_prot  = (const int*)d_in[7];
  const float* nlm_w = (const float*)d_in[8];
  const float* nlm_b = (const float*)d_in[9];
  const float* nlp_w = (const float*)d_in[10];
  const float* nlp_b = (const float*)d_in[11];
  const float* elm_w = (const float*)d_in[12];
  const float* elm_b = (const float*)d_in[13];
  const float* elp_w = (const float*)d_in[14];
  const float* elp_b = (const float*)d_in[15];
  const float* mol_w1 = (const float*)d_in[16];
  const float* mol_b1 = (const float*)d_in[17];
  const float* mol_w2 = (const float*)d_in[18];
  const float* mol_b2 = (const float*)d_in[19];
  const float* prot_w1 = (const float*)d_in[20];
  const float* prot_b1 = (const float*)d_in[21];
  const float* prot_w2 = (const float*)d_in[22];
  const float* prot_b2 = (const float*)d_in[23];
  const float* mp_wq = (const float*)d_in[24];
  const float* mp_bq = (const float*)d_in[25];
  const float* mp_wk = (const float*)d_in[26];
  const float* mp_bk = (const float*)d_in[27];
  const float* mp_wv = (const float*)d_in[28];
  const float* mp_bv = (const float*)d_in[29];
  const float* pm_wq = (const float*)d_in[30];
  const float* pm_bq = (const float*)d_in[31];
  const float* pm_wk = (const float*)d_in[32];
  const float* pm_bk = (const float*)d_in[33];
  const float* pm_wv = (const float*)d_in[34];
  const float* pm_bv = (const float*)d_in[35];
  const float* fc1_w = (const float*)d_in[36];
  const float* fc1_b = (const float*)d_in[37];
  const float* fc2_w = (const float*)d_in[38];
  const float* fc2_b = (const float*)d_in[39];
  float* out = (float*)d_out;

  float* ws = (float*)d_ws;
  const size_t SZ = (size_t)4096 * 256;  // 1 Mi floats
  float* hm  = ws + 0 * SZ;
  float* hp  = ws + 1 * SZ;
  float* agg = ws + 2 * SZ;
  float* t1  = ws + 3 * SZ;
  float* Qb  = ws + 4 * SZ;
  float* Kb  = ws + 5 * SZ;
  float* Vb  = ws + 6 * SZ;
  float* hmc = ws + 7 * SZ;
  float* hpc = ws + 8 * SZ;
  float* zb  = ws + 9 * SZ;     // 32*512
  float* cnt = zb + 32 * 512;   // 64
  float* fch = cnt + 64;        // 32*256

  const dim3 ggrid(64, 4), gblk(256);

  // node embeddings
  k_node_embed<<<NMOL, 256, 0, stream>>>(x_mol, nlm_w, nlm_b, hm, 8);
  k_node_embed<<<NPROT, 256, 0, stream>>>(x_prot, nlp_w, nlp_b, hp, 4);

  // GINE stacks (2 layers each)
  for (int l = 0; l < 2; ++l) {
    hipMemsetAsync(agg, 0, SZ * 4, stream);
    k_gine_agg<<<NEDGE, 256, 0, stream>>>(hm, ea_mol, ei_mol, elm_w, elm_b, agg, NEDGE);
    k_gemm<true, true><<<ggrid, gblk, 0, stream>>>(hm, agg, mol_w1 + l * 65536,
                                                   mol_b1 + l * 256, t1, 4096, 256, 256);
    k_gemm<true, false><<<ggrid, gblk, 0, stream>>>(t1, nullptr, mol_w2 + l * 65536,
                                                    mol_b2 + l * 256, hm, 4096, 256, 256);
  }
  for (int l = 0; l < 2; ++l) {
    hipMemsetAsync(agg, 0, SZ * 4, stream);
    k_gine_agg<<<NEDGE, 256, 0, stream>>>(hp, ea_prot, ei_prot, elp_w, elp_b, agg, NEDGE);
    k_gemm<true, true><<<ggrid, gblk, 0, stream>>>(hp, agg, prot_w1 + l * 65536,
                                                   prot_b1 + l * 256, t1, 4096, 256, 256);
    k_gemm<true, false><<<ggrid, gblk, 0, stream>>>(t1, nullptr, prot_w2 + l * 65536,
                                                    prot_b2 + l * 256, hp, 4096, 256, 256);
  }

  // cross attention mol <- prot
  k_gemm<false, false><<<ggrid, gblk, 0, stream>>>(hm, nullptr, mp_wq, mp_bq, Qb, 4096, 256, 256);
  k_gemm<false, false><<<ggrid, gblk, 0, stream>>>(hp, nullptr, mp_wk, mp_bk, Kb, 4096, 256, 256);
  k_gemm<false, false><<<ggrid, gblk, 0, stream>>>(hp, nullptr, mp_wv, mp_bv, Vb, 4096, 256, 256);
  k_attn<<<dim3(64, 4), 256, 0, stream>>>(Qb, Kb, Vb, hm, hmc, 4096, 4096);

  // cross attention prot <- mol
  k_gemm<false, false><<<ggrid, gblk, 0, stream>>>(hp, nullptr, pm_wq, pm_bq, Qb, 4096, 256, 256);
  k_gemm<false, false><<<ggrid, gblk, 0, stream>>>(hm, nullptr, pm_wk, pm_bk, Kb, 4096, 256, 256);
  k_gemm<false, false><<<ggrid, gblk, 0, stream>>>(hm, nullptr, pm_wv, pm_bv, Vb, 4096, 256, 256);
  k_attn<<<dim3(64, 4), 256, 0, stream>>>(Qb, Kb, Vb, hp, hpc, 4096, 4096);

  // pooling + head
  hipMemsetAsync(zb, 0, (32 * 512 + 64) * 4, stream);
  k_segsum<<<NMOL, 256, 0, stream>>>(hmc, b_mol, zb, cnt);
  k_segsum<<<NPROT, 256, 0, stream>>>(hpc, b_prot, zb + 256, cnt + 32);
  k_segdiv<<<64, 256, 0, stream>>>(zb, cnt);
  k_fc1<<<32, 256, 0, stream>>>(zb, fc1_w, fc1_b, fch);
  k_fc2<<<1, 64, 0, stream>>>(fch, fc2_w, fc2_b, out);
}